// Round 5
// baseline (106.961 us; speedup 1.0000x reference)
//
#include <hip/hip_runtime.h>
#include <cstdint>
#include <cmath>

typedef unsigned short u16;
typedef __bf16 bf16x8 __attribute__((ext_vector_type(8)));
typedef float f32x4 __attribute__((ext_vector_type(4)));

#define B_SZ   1024
#define IN_SZ  512
#define U_SZ   512
#define KTOT   4608      // IN_SZ * 9 (8 spline bases + 1 silu slot)
#define SPLITS 8
#define KLEN   576       // KTOT / SPLITS
#define BK     32
#define KITERS 18        // KLEN / BK

__device__ __forceinline__ u16 f2bf(float f) {
  __bf16 h = (__bf16)f;
  return __builtin_bit_cast(u16, h);
}

// async global->LDS, 16B per lane. LDS dest must be wave-uniform base + lane*16.
__device__ __forceinline__ void async16(const void* g, void* l) {
  __builtin_amdgcn_global_load_lds(
      (__attribute__((address_space(1))) void*)(g),
      (__attribute__((address_space(3))) void*)(l), 16u, 0, 0u);
}

// ---------------------------------------------------------------------------
// One fused prep launch, grid-partitioned by blockIdx.x:
//   [0,512):    W'[o][i*9+k] = (k<8 ? SK[i][k][o] : 1)*SF[i][o], O-major (LDS
//               transpose, pad 66 so the strided read is conflict-free).
//               Block 0 additionally zeroes the 32 split-K tile counters.
//   [512,2560): A[b][i*9+k] = cubic B-spline bases + silu (LDS-staged so the
//               global write is coalesced u16 streams, not 9x2B scalar)
// ---------------------------------------------------------------------------
__global__ void __launch_bounds__(256) prep_all(const float* __restrict__ SK,
                                                const float* __restrict__ SF,
                                                const float* __restrict__ X,
                                                u16* __restrict__ WT,
                                                u16* __restrict__ A,
                                                int* __restrict__ cnt) {
  const int bx = blockIdx.x;
  const int tid = threadIdx.x;

  if (bx < 512) {
    if (bx == 0 && tid < 32) cnt[tid] = 0;   // re-zero every call (ws poisoned)
    __shared__ u16 tile[72 * 66];
    const int o0 = (bx & 7) * 64;
    const int i0 = (bx >> 3) * 8;
    const int oo = tid & 63, grp = tid >> 6;
    for (int tr = grp; tr < 72; tr += 4) {
      int i = i0 + tr / 9;
      int k = tr % 9;
      float sf = SF[(size_t)i * U_SZ + o0 + oo];
      float v  = (k < 8) ? SK[((size_t)i * 8 + k) * U_SZ + o0 + oo] * sf : sf;
      tile[tr * 66 + oo] = f2bf(v);
    }
    __syncthreads();
    const int t0 = i0 * 9;
    for (int idx = tid; idx < 72 * 64; idx += 256) {
      int ol = idx / 72;
      int c  = idx - ol * 72;
      WT[(size_t)(o0 + ol) * KTOT + t0 + c] = tile[c * 66 + ol];
    }
  } else {
    __shared__ u16 st[2304];
    const int gid0 = (bx - 512) * 256;          // first (b*512+i) of this block
    const float x = X[gid0 + tid];

    const float T0 = -2.2f, H = 0.4f;
    float b0[11], b1[10], b2[9], b3[8];
#pragma unroll
    for (int j = 0; j < 11; ++j) {
      float tj  = T0 + H * j;
      float tj1 = T0 + H * (j + 1);
      b0[j] = (x >= tj && x < tj1) ? 1.0f : 0.0f;
    }
#pragma unroll
    for (int j = 0; j < 10; ++j) {
      float tj  = T0 + H * j;
      float tj2 = T0 + H * (j + 2);
      b1[j] = (x - tj) * 2.5f * b0[j] + (tj2 - x) * 2.5f * b0[j + 1];
    }
#pragma unroll
    for (int j = 0; j < 9; ++j) {
      float tj  = T0 + H * j;
      float tj3 = T0 + H * (j + 3);
      b2[j] = (x - tj) * 1.25f * b1[j] + (tj3 - x) * 1.25f * b1[j + 1];
    }
#pragma unroll
    for (int j = 0; j < 8; ++j) {
      float tj  = T0 + H * j;
      float tj4 = T0 + H * (j + 4);
      b3[j] = (x - tj) * (1.0f / 1.2f) * b2[j] + (tj4 - x) * (1.0f / 1.2f) * b2[j + 1];
    }
    float sil = x / (1.0f + expf(-x));

#pragma unroll
    for (int k = 0; k < 8; ++k) st[tid * 9 + k] = f2bf(b3[k]);
    st[tid * 9 + 8] = f2bf(sil);
    __syncthreads();
    u16* dst = A + (size_t)gid0 * 9;
#pragma unroll
    for (int j = 0; j < 9; ++j) dst[j * 256 + tid] = st[j * 256 + tid];
  }
}

// ---------------------------------------------------------------------------
// Split-K bf16 MFMA GEMM with fused serial-reduction epilogue.
// 256 threads = 4 waves in 2x2; each wave a 64x64 subtile (4x4 frags of
// 16x16x32). BK=32, double-buffered LDS with XOR-chunk swizzle, width-16
// global_load_lds staging. Each block writes its partial to P[z]; the last
// split block per (x,y) tile (device-scope counter) re-reads the 8 partials
// in fixed z-order, adds bias, writes out. grid (8,4,8) x 256.
// ---------------------------------------------------------------------------
__global__ void __launch_bounds__(256) gemm_kan(const u16* __restrict__ A,
                                                const u16* __restrict__ WT,
                                                const float* __restrict__ bias,
                                                float* __restrict__ P,
                                                int* __restrict__ cnt,
                                                float* __restrict__ out) {
  __shared__ __align__(16) u16 sA[2][128 * BK];   // 8 KB each buf
  __shared__ __align__(16) u16 sB[2][128 * BK];
  __shared__ int s_last;

  const int t    = threadIdx.x;
  const int lane = t & 63;
  const int w    = t >> 6;
  const int wr   = w >> 1;          // wave m-half (0/1)
  const int wn   = w & 1;           // wave n-half (0/1)
  const int m0   = blockIdx.x * 128;
  const int n0   = blockIdx.y * 128;
  const int kbase = blockIdx.z * KLEN;

  // staging: idx = j*256+t -> (row = idx>>2, c = idx&3); LDS pos (row,c) gets
  // global chunk g = c ^ (row&3). Dest offset idx*16 = wave-uniform + lane*16.
  const int srow = t >> 2, sc = t & 3;
  const int sg0 = (sc ^ (srow & 3)) * 8;              // element offset of chunk
  const int srow1 = (t + 256) >> 2, sc1 = t & 3;      // j=1: row += 64
  const int sg1 = (sc1 ^ (srow1 & 3)) * 8;
  const u16* gA0 = A  + (size_t)(m0 + srow)  * KTOT + sg0;
  const u16* gA1 = A  + (size_t)(m0 + srow1) * KTOT + sg1;
  const u16* gB0 = WT + (size_t)(n0 + srow)  * KTOT + sg0;
  const u16* gB1 = WT + (size_t)(n0 + srow1) * KTOT + sg1;

  f32x4 acc[4][4];
#pragma unroll
  for (int i = 0; i < 4; ++i)
#pragma unroll
    for (int j = 0; j < 4; ++j) acc[i][j] = (f32x4)0.0f;

  auto stage = [&](int buf, int k0) {
    char* lA = (char*)(&sA[buf][0]) + t * 16;
    char* lB = (char*)(&sB[buf][0]) + t * 16;
    async16(gA0 + k0, lA);
    async16(gA1 + k0, lA + 4096);
    async16(gB0 + k0, lB);
    async16(gB1 + k0, lB + 4096);
  };

  stage(0, kbase);

  const int m = lane & 15, q = lane >> 4;
  // frag read: row = half*64 + tt*16 + m; chunk pos = q ^ (row&3) = q ^ (m&3)
  const int qs = (q ^ (m & 3)) * 16;   // byte offset within row
  const char* fA = (const char*)(&sA[0][0]) + (wr * 64 + m) * (BK * 2) + qs;
  const char* fB = (const char*)(&sB[0][0]) + (wn * 64 + m) * (BK * 2) + qs;
  const int bufstep = 128 * BK * 2;    // bytes between dbuf buffers

#pragma unroll
  for (int it = 0; it < KITERS; ++it) {
    const int cur = it & 1;
    __syncthreads();                   // drains vmcnt: buf[cur] ready
    if (it + 1 < KITERS) stage(cur ^ 1, kbase + (it + 1) * BK);

    bf16x8 af[4], bfv[4];
#pragma unroll
    for (int tt = 0; tt < 4; ++tt)
      af[tt] = *(const bf16x8*)(fA + cur * bufstep + tt * 16 * (BK * 2));
#pragma unroll
    for (int tt = 0; tt < 4; ++tt)
      bfv[tt] = *(const bf16x8*)(fB + cur * bufstep + tt * 16 * (BK * 2));
#pragma unroll
    for (int mt = 0; mt < 4; ++mt)
#pragma unroll
      for (int nt = 0; nt < 4; ++nt)
        acc[mt][nt] = __builtin_amdgcn_mfma_f32_16x16x32_bf16(
            af[mt], bfv[nt], acc[mt][nt], 0, 0, 0);
  }

  // ---- write partial: C/D layout col = lane&15, row = (lane>>4)*4 + reg ----
  float* Pp = P + (size_t)blockIdx.z * (B_SZ * U_SZ);
#pragma unroll
  for (int mt = 0; mt < 4; ++mt)
#pragma unroll
    for (int rr = 0; rr < 4; ++rr) {
      int row = m0 + wr * 64 + mt * 16 + q * 4 + rr;
      size_t rb = (size_t)row * U_SZ + n0 + wn * 64 + m;
#pragma unroll
      for (int nt = 0; nt < 4; ++nt) Pp[rb + nt * 16] = acc[mt][nt][rr];
    }

  // ---- serial split-K reduction: last block per tile finalizes ----
  __syncthreads();                     // all partial stores issued
  if (t == 0) {
    __threadfence();                   // device-scope release (cross-XCD)
    s_last = atomicAdd(&cnt[blockIdx.x * 4 + blockIdx.y], 1);
  }
  __syncthreads();
  if (s_last == SPLITS - 1) {
    __threadfence();                   // acquire: invalidate stale L1/L2 lines
    const f32x4* P4 = (const f32x4*)P;
    const f32x4* b4 = (const f32x4*)bias;
    f32x4* o4 = (f32x4*)out;
    const int cb = n0 >> 2;            // f32x4 col base (n0/4)
#pragma unroll
    for (int j = 0; j < 16; ++j) {
      int idx = j * 256 + t;           // 4096 f32x4 in this 128x128 tile
      int r   = idx >> 5;              // 32 f32x4 per row
      int c4  = idx & 31;
      size_t e = (size_t)(m0 + r) * (U_SZ / 4) + cb + c4;
      f32x4 v = b4[cb + c4];
#pragma unroll
      for (int z = 0; z < SPLITS; ++z)
        v += P4[(size_t)z * (B_SZ * U_SZ / 4) + e];
      o4[e] = v;
    }
  }
}

extern "C" void kernel_launch(void* const* d_in, const int* in_sizes, int n_in,
                              void* d_out, int out_size, void* d_ws, size_t ws_size,
                              hipStream_t stream) {
  const float* X    = (const float*)d_in[0];  // (1024, 512)
  const float* SK   = (const float*)d_in[1];  // (512, 8, 512)
  const float* SF   = (const float*)d_in[2];  // (512, 512)
  const float* bias = (const float*)d_in[3];  // (512,)

  char* ws = (char*)d_ws;
  u16*   WT  = (u16*)ws;                                   // 512*4608*2  = 4,718,592 B
  u16*   A   = (u16*)(ws + 4718592);                       // 1024*4608*2 = 9,437,184 B
  float* P   = (float*)(ws + 4718592 + 9437184);           // 8*1024*512*4 = 16,777,216 B
  int*   cnt = (int*)(ws + 4718592 + 9437184 + 16777216);  // 32 ints

  hipLaunchKernelGGL(prep_all, dim3(2560),    dim3(256), 0, stream, SK, SF, X, WT, A, cnt);
  hipLaunchKernelGGL(gemm_kan, dim3(8, 4, 8), dim3(256), 0, stream, A, WT, bias, P, cnt, (float*)d_out);
}

// Round 6
// 90.517 us; speedup vs baseline: 1.1817x; 1.1817x over previous
//
#include <hip/hip_runtime.h>
#include <cstdint>
#include <cmath>

typedef unsigned short u16;
typedef __bf16 bf16x8 __attribute__((ext_vector_type(8)));
typedef float f32x4 __attribute__((ext_vector_type(4)));

#define B_SZ   1024
#define IN_SZ  512
#define U_SZ   512
#define KTOT   4608      // IN_SZ * 9 (8 spline bases + 1 silu slot)
#define SPLITS 8
#define KLEN   576       // KTOT / SPLITS
#define BK     32
#define KITERS 18        // KLEN / BK

__device__ __forceinline__ u16 f2bf(float f) {
  __bf16 h = (__bf16)f;
  return __builtin_bit_cast(u16, h);
}

// async global->LDS, 16B per lane. LDS dest must be wave-uniform base + lane*16.
__device__ __forceinline__ void async16(const void* g, void* l) {
  __builtin_amdgcn_global_load_lds(
      (__attribute__((address_space(1))) void*)(g),
      (__attribute__((address_space(3))) void*)(l), 16u, 0, 0u);
}

// ---------------------------------------------------------------------------
// One fused prep launch, grid-partitioned by blockIdx.x:
//   [0,512):    W'[o][i*9+k] = (k<8 ? SK[i][k][o] : 1)*SF[i][o], O-major (LDS
//               transpose, pad 66 so the strided read is conflict-free)
//   [512,2560): A[b][i*9+k] = cubic B-spline bases + silu (LDS-staged so the
//               global write is coalesced u16 streams, not 9x2B scalar)
// ---------------------------------------------------------------------------
__global__ void __launch_bounds__(256) prep_all(const float* __restrict__ SK,
                                                const float* __restrict__ SF,
                                                const float* __restrict__ X,
                                                u16* __restrict__ WT,
                                                u16* __restrict__ A) {
  const int bx = blockIdx.x;
  const int tid = threadIdx.x;

  if (bx < 512) {
    __shared__ u16 tile[72 * 66];
    const int o0 = (bx & 7) * 64;
    const int i0 = (bx >> 3) * 8;
    const int oo = tid & 63, grp = tid >> 6;
    for (int tr = grp; tr < 72; tr += 4) {
      int i = i0 + tr / 9;
      int k = tr % 9;
      float sf = SF[(size_t)i * U_SZ + o0 + oo];
      float v  = (k < 8) ? SK[((size_t)i * 8 + k) * U_SZ + o0 + oo] * sf : sf;
      tile[tr * 66 + oo] = f2bf(v);
    }
    __syncthreads();
    const int t0 = i0 * 9;
    for (int idx = tid; idx < 72 * 64; idx += 256) {
      int ol = idx / 72;
      int c  = idx - ol * 72;
      WT[(size_t)(o0 + ol) * KTOT + t0 + c] = tile[c * 66 + ol];
    }
  } else {
    __shared__ u16 st[2304];
    const int gid0 = (bx - 512) * 256;          // first (b*512+i) of this block
    const float x = X[gid0 + tid];

    const float T0 = -2.2f, H = 0.4f;
    float b0[11], b1[10], b2[9], b3[8];
#pragma unroll
    for (int j = 0; j < 11; ++j) {
      float tj  = T0 + H * j;
      float tj1 = T0 + H * (j + 1);
      b0[j] = (x >= tj && x < tj1) ? 1.0f : 0.0f;
    }
#pragma unroll
    for (int j = 0; j < 10; ++j) {
      float tj  = T0 + H * j;
      float tj2 = T0 + H * (j + 2);
      b1[j] = (x - tj) * 2.5f * b0[j] + (tj2 - x) * 2.5f * b0[j + 1];
    }
#pragma unroll
    for (int j = 0; j < 9; ++j) {
      float tj  = T0 + H * j;
      float tj3 = T0 + H * (j + 3);
      b2[j] = (x - tj) * 1.25f * b1[j] + (tj3 - x) * 1.25f * b1[j + 1];
    }
#pragma unroll
    for (int j = 0; j < 8; ++j) {
      float tj  = T0 + H * j;
      float tj4 = T0 + H * (j + 4);
      b3[j] = (x - tj) * (1.0f / 1.2f) * b2[j] + (tj4 - x) * (1.0f / 1.2f) * b2[j + 1];
    }
    float sil = x / (1.0f + expf(-x));

#pragma unroll
    for (int k = 0; k < 8; ++k) st[tid * 9 + k] = f2bf(b3[k]);
    st[tid * 9 + 8] = f2bf(sil);
    __syncthreads();
    u16* dst = A + (size_t)gid0 * 9;
#pragma unroll
    for (int j = 0; j < 9; ++j) dst[j * 256 + tid] = st[j * 256 + tid];
  }
}

// ---------------------------------------------------------------------------
// Split-K bf16 MFMA GEMM: P[s] = A[m0:+128, ks] * WT[n0:+128, ks]^T
// 256 threads = 4 waves in 2x2; each wave a 64x64 subtile (4x4 frags of
// 16x16x32). BK=32, double-buffered LDS with XOR-chunk swizzle (bank-optimal
// frag reads), global_load_lds width-16 staging. Partials stored bf16
// (halves P traffic; error budget ~0.01 vs 0.064 threshold — R5 post-mortem).
// grid (8,4,8) x 256.
// ---------------------------------------------------------------------------
__global__ void __launch_bounds__(256) gemm_kan(const u16* __restrict__ A,
                                                const u16* __restrict__ WT,
                                                u16* __restrict__ P) {
  __shared__ __align__(16) u16 sA[2][128 * BK];   // 8 KB each buf
  __shared__ __align__(16) u16 sB[2][128 * BK];

  const int t    = threadIdx.x;
  const int lane = t & 63;
  const int w    = t >> 6;
  const int wr   = w >> 1;          // wave m-half (0/1)
  const int wn   = w & 1;           // wave n-half (0/1)
  const int m0   = blockIdx.x * 128;
  const int n0   = blockIdx.y * 128;
  const int kbase = blockIdx.z * KLEN;

  // staging: idx = j*256+t -> (row = idx>>2, c = idx&3); LDS pos (row,c) gets
  // global chunk g = c ^ (row&3). Dest offset idx*16 = wave-uniform + lane*16.
  const int srow = t >> 2, sc = t & 3;
  const int sg0 = (sc ^ (srow & 3)) * 8;              // element offset of chunk
  const int srow1 = (t + 256) >> 2, sc1 = t & 3;      // j=1: row += 64
  const int sg1 = (sc1 ^ (srow1 & 3)) * 8;
  const u16* gA0 = A  + (size_t)(m0 + srow)  * KTOT + sg0;
  const u16* gA1 = A  + (size_t)(m0 + srow1) * KTOT + sg1;
  const u16* gB0 = WT + (size_t)(n0 + srow)  * KTOT + sg0;
  const u16* gB1 = WT + (size_t)(n0 + srow1) * KTOT + sg1;

  f32x4 acc[4][4];
#pragma unroll
  for (int i = 0; i < 4; ++i)
#pragma unroll
    for (int j = 0; j < 4; ++j) acc[i][j] = (f32x4)0.0f;

  auto stage = [&](int buf, int k0) {
    char* lA = (char*)(&sA[buf][0]) + t * 16;
    char* lB = (char*)(&sB[buf][0]) + t * 16;
    async16(gA0 + k0, lA);
    async16(gA1 + k0, lA + 4096);
    async16(gB0 + k0, lB);
    async16(gB1 + k0, lB + 4096);
  };

  stage(0, kbase);

  const int m = lane & 15, q = lane >> 4;
  // frag read: row = half*64 + tt*16 + m; chunk pos = q ^ (row&3) = q ^ (m&3)
  const int qs = (q ^ (m & 3)) * 16;   // byte offset within row
  const char* fA = (const char*)(&sA[0][0]) + (wr * 64 + m) * (BK * 2) + qs;
  const char* fB = (const char*)(&sB[0][0]) + (wn * 64 + m) * (BK * 2) + qs;
  const int bufstep = 128 * BK * 2;    // bytes between dbuf buffers

#pragma unroll
  for (int it = 0; it < KITERS; ++it) {
    const int cur = it & 1;
    __syncthreads();                   // drains vmcnt: buf[cur] ready
    if (it + 1 < KITERS) stage(cur ^ 1, kbase + (it + 1) * BK);

    bf16x8 af[4], bfv[4];
#pragma unroll
    for (int tt = 0; tt < 4; ++tt)
      af[tt] = *(const bf16x8*)(fA + cur * bufstep + tt * 16 * (BK * 2));
#pragma unroll
    for (int tt = 0; tt < 4; ++tt)
      bfv[tt] = *(const bf16x8*)(fB + cur * bufstep + tt * 16 * (BK * 2));
#pragma unroll
    for (int mt = 0; mt < 4; ++mt)
#pragma unroll
      for (int nt = 0; nt < 4; ++nt)
        acc[mt][nt] = __builtin_amdgcn_mfma_f32_16x16x32_bf16(
            af[mt], bfv[nt], acc[mt][nt], 0, 0, 0);
  }

  // epilogue: C/D layout col = lane&15, row = (lane>>4)*4 + reg; bf16 stores
  u16* Pp = P + (size_t)blockIdx.z * (B_SZ * U_SZ);
#pragma unroll
  for (int mt = 0; mt < 4; ++mt)
#pragma unroll
    for (int rr = 0; rr < 4; ++rr) {
      int row = m0 + wr * 64 + mt * 16 + q * 4 + rr;
      size_t rb = (size_t)row * U_SZ + n0 + wn * 64 + m;
#pragma unroll
      for (int nt = 0; nt < 4; ++nt) Pp[rb + nt * 16] = f2bf(acc[mt][nt][rr]);
    }
}

// ---------------------------------------------------------------------------
// out = sum_s bf16(P[s]) + bias, fp32 accumulate. grid 256 x 256; each thread
// one bf16x8 (8 consecutive outputs): 16B load per split, 2 f32x4 stores.
// ---------------------------------------------------------------------------
__global__ void reduce_kernel(const u16* __restrict__ P,
                              const float* __restrict__ bias,
                              float* __restrict__ out) {
  const int idx = blockIdx.x * 256 + threadIdx.x;  // bf16x8 index, 0..65535
  const int col8 = (idx & 63) * 8;                 // 64 groups of 8 per row
  float acc[8];
#pragma unroll
  for (int j = 0; j < 8; ++j) acc[j] = bias[col8 + j];
#pragma unroll
  for (int s = 0; s < SPLITS; ++s) {
    bf16x8 v = ((const bf16x8*)P)[(size_t)s * (B_SZ * U_SZ / 8) + idx];
#pragma unroll
    for (int j = 0; j < 8; ++j) acc[j] += (float)v[j];
  }
  f32x4 o0, o1;
#pragma unroll
  for (int j = 0; j < 4; ++j) { o0[j] = acc[j]; o1[j] = acc[4 + j]; }
  f32x4* o4 = (f32x4*)out;
  o4[idx * 2]     = o0;
  o4[idx * 2 + 1] = o1;
}

extern "C" void kernel_launch(void* const* d_in, const int* in_sizes, int n_in,
                              void* d_out, int out_size, void* d_ws, size_t ws_size,
                              hipStream_t stream) {
  const float* X    = (const float*)d_in[0];  // (1024, 512)
  const float* SK   = (const float*)d_in[1];  // (512, 8, 512)
  const float* SF   = (const float*)d_in[2];  // (512, 512)
  const float* bias = (const float*)d_in[3];  // (512,)

  char* ws = (char*)d_ws;
  u16* WT = (u16*)ws;                       // 512*4608*2  = 4,718,592 B
  u16* A  = (u16*)(ws + 4718592);           // 1024*4608*2 = 9,437,184 B
  u16* P  = (u16*)(ws + 4718592 + 9437184); // 8*1024*512*2 = 8,388,608 B

  hipLaunchKernelGGL(prep_all,      dim3(2560),    dim3(256), 0, stream, SK, SF, X, WT, A);
  hipLaunchKernelGGL(gemm_kan,      dim3(8, 4, 8), dim3(256), 0, stream, A, WT, P);
  hipLaunchKernelGGL(reduce_kernel, dim3(256),     dim3(256), 0, stream, P, bias, (float*)d_out);
}

// Round 7
// 89.335 us; speedup vs baseline: 1.1973x; 1.0132x over previous
//
#include <hip/hip_runtime.h>
#include <cstdint>
#include <cmath>

typedef unsigned short u16;
typedef __bf16 bf16x8 __attribute__((ext_vector_type(8)));
typedef float f32x4 __attribute__((ext_vector_type(4)));

#define B_SZ   1024
#define IN_SZ  512
#define U_SZ   512
#define KTOT   4608      // IN_SZ * 9 (8 spline bases + 1 silu slot)
#define SPLITS 8
#define KLEN   576       // KTOT / SPLITS
#define BK     64
#define KITERS 9         // KLEN / BK

__device__ __forceinline__ u16 f2bf(float f) {
  __bf16 h = (__bf16)f;
  return __builtin_bit_cast(u16, h);
}

// async global->LDS, 16B per lane. LDS dest must be wave-uniform base + lane*16.
__device__ __forceinline__ void async16(const void* g, void* l) {
  __builtin_amdgcn_global_load_lds(
      (__attribute__((address_space(1))) void*)(g),
      (__attribute__((address_space(3))) void*)(l), 16u, 0, 0u);
}

// ---------------------------------------------------------------------------
// One fused prep launch, grid-partitioned by blockIdx.x:
//   [0,512):    W'[o][i*9+k] = (k<8 ? SK[i][k][o] : 1)*SF[i][o], O-major (LDS
//               transpose, pad 66 so the strided read is conflict-free)
//   [512,2560): A[b][i*9+k] = cubic B-spline bases + silu (LDS-staged so the
//               global write is coalesced u16 streams, not 9x2B scalar)
// ---------------------------------------------------------------------------
__global__ void __launch_bounds__(256) prep_all(const float* __restrict__ SK,
                                                const float* __restrict__ SF,
                                                const float* __restrict__ X,
                                                u16* __restrict__ WT,
                                                u16* __restrict__ A) {
  const int bx = blockIdx.x;
  const int tid = threadIdx.x;

  if (bx < 512) {
    __shared__ u16 tile[72 * 66];
    const int o0 = (bx & 7) * 64;
    const int i0 = (bx >> 3) * 8;
    const int oo = tid & 63, grp = tid >> 6;
    for (int tr = grp; tr < 72; tr += 4) {
      int i = i0 + tr / 9;
      int k = tr % 9;
      float sf = SF[(size_t)i * U_SZ + o0 + oo];
      float v  = (k < 8) ? SK[((size_t)i * 8 + k) * U_SZ + o0 + oo] * sf : sf;
      tile[tr * 66 + oo] = f2bf(v);
    }
    __syncthreads();
    const int t0 = i0 * 9;
    for (int idx = tid; idx < 72 * 64; idx += 256) {
      int ol = idx / 72;
      int c  = idx - ol * 72;
      WT[(size_t)(o0 + ol) * KTOT + t0 + c] = tile[c * 66 + ol];
    }
  } else {
    __shared__ u16 st[2304];
    const int gid0 = (bx - 512) * 256;          // first (b*512+i) of this block
    const float x = X[gid0 + tid];

    const float T0 = -2.2f, H = 0.4f;
    float b0[11], b1[10], b2[9], b3[8];
#pragma unroll
    for (int j = 0; j < 11; ++j) {
      float tj  = T0 + H * j;
      float tj1 = T0 + H * (j + 1);
      b0[j] = (x >= tj && x < tj1) ? 1.0f : 0.0f;
    }
#pragma unroll
    for (int j = 0; j < 10; ++j) {
      float tj  = T0 + H * j;
      float tj2 = T0 + H * (j + 2);
      b1[j] = (x - tj) * 2.5f * b0[j] + (tj2 - x) * 2.5f * b0[j + 1];
    }
#pragma unroll
    for (int j = 0; j < 9; ++j) {
      float tj  = T0 + H * j;
      float tj3 = T0 + H * (j + 3);
      b2[j] = (x - tj) * 1.25f * b1[j] + (tj3 - x) * 1.25f * b1[j + 1];
    }
#pragma unroll
    for (int j = 0; j < 8; ++j) {
      float tj  = T0 + H * j;
      float tj4 = T0 + H * (j + 4);
      b3[j] = (x - tj) * (1.0f / 1.2f) * b2[j] + (tj4 - x) * (1.0f / 1.2f) * b2[j + 1];
    }
    float sil = x / (1.0f + expf(-x));

#pragma unroll
    for (int k = 0; k < 8; ++k) st[tid * 9 + k] = f2bf(b3[k]);
    st[tid * 9 + 8] = f2bf(sil);
    __syncthreads();
    u16* dst = A + (size_t)gid0 * 9;
#pragma unroll
    for (int j = 0; j < 9; ++j) dst[j * 256 + tid] = st[j * 256 + tid];
  }
}

// ---------------------------------------------------------------------------
// Split-K bf16 MFMA GEMM: P[s] = A[m0:+128, ks] * WT[n0:+128, ks]^T
// 256 threads = 4 waves in 2x2; each wave a 64x64 subtile (4x4 frags of
// 16x16x32). BK=64 (9 barriers instead of 18 — at 1 wave/SIMD the per-barrier
// vmcnt drain ~350cyc is fully exposed, R6 post-mortem), double-buffered LDS
// (64 KB total; occupancy is grid-limited so LDS growth is free) with XOR
// chunk swizzle (8 chunks/row, conflict-free frag reads), width-16
// global_load_lds staging. bf16 partials. grid (8,4,8) x 256.
// ---------------------------------------------------------------------------
__global__ void __launch_bounds__(256) gemm_kan(const u16* __restrict__ A,
                                                const u16* __restrict__ WT,
                                                u16* __restrict__ P) {
  __shared__ __align__(16) u16 sA[2][128 * BK];   // 16 KB each buf
  __shared__ __align__(16) u16 sB[2][128 * BK];

  const int t    = threadIdx.x;
  const int lane = t & 63;
  const int w    = t >> 6;
  const int wr   = w >> 1;          // wave m-half (0/1)
  const int wn   = w & 1;           // wave n-half (0/1)
  const int m0   = blockIdx.x * 128;
  const int n0   = blockIdx.y * 128;
  const int kbase = blockIdx.z * KLEN;

  // staging: idx = j*256+t -> (row = idx>>3, c = t&7); LDS pos (row,c) gets
  // global chunk c ^ (row&7). row&7 = (t>>3)&7 for all j, so the XOR'd
  // element offset sg is j-invariant. Dest = base + t*16 + j*4096.
  const int srow = t >> 3;
  const int sg   = (((t & 7) ^ (srow & 7))) * 8;      // element offset of chunk
  const u16* gA = A  + (size_t)(m0 + srow) * KTOT + sg;
  const u16* gB = WT + (size_t)(n0 + srow) * KTOT + sg;

  f32x4 acc[4][4];
#pragma unroll
  for (int i = 0; i < 4; ++i)
#pragma unroll
    for (int j = 0; j < 4; ++j) acc[i][j] = (f32x4)0.0f;

  auto stage = [&](int buf, int k0) {
    char* lA = (char*)(&sA[buf][0]) + t * 16;
    char* lB = (char*)(&sB[buf][0]) + t * 16;
#pragma unroll
    for (int j = 0; j < 4; ++j) {
      async16(gA + k0 + (size_t)j * 32 * KTOT, lA + j * 4096);
      async16(gB + k0 + (size_t)j * 32 * KTOT, lB + j * 4096);
    }
  };

  stage(0, kbase);

  const int m = lane & 15, q = lane >> 4;
  // frag read: row = half*64 + tt*16 + m (row&7 = m&7); s-step s reads chunk
  // (s*4+q) ^ (m&7) within the 8-chunk (128B) row.
  const int qs0 = ((q)     ^ (m & 7)) * 16;  // byte offset, s=0
  const int qs1 = ((4 + q) ^ (m & 7)) * 16;  // byte offset, s=1
  const char* fA = (const char*)(&sA[0][0]) + (wr * 64 + m) * (BK * 2);
  const char* fB = (const char*)(&sB[0][0]) + (wn * 64 + m) * (BK * 2);
  const int bufstep = 128 * BK * 2;    // bytes between dbuf buffers

#pragma unroll
  for (int it = 0; it < KITERS; ++it) {
    const int cur = it & 1;
    __syncthreads();                   // drains vmcnt: buf[cur] ready
    if (it + 1 < KITERS) stage(cur ^ 1, kbase + (it + 1) * BK);

#pragma unroll
    for (int s = 0; s < 2; ++s) {
      const int qs = s ? qs1 : qs0;
      bf16x8 af[4], bfv[4];
#pragma unroll
      for (int tt = 0; tt < 4; ++tt)
        af[tt] = *(const bf16x8*)(fA + cur * bufstep + tt * 16 * (BK * 2) + qs);
#pragma unroll
      for (int tt = 0; tt < 4; ++tt)
        bfv[tt] = *(const bf16x8*)(fB + cur * bufstep + tt * 16 * (BK * 2) + qs);
#pragma unroll
      for (int mt = 0; mt < 4; ++mt)
#pragma unroll
        for (int nt = 0; nt < 4; ++nt)
          acc[mt][nt] = __builtin_amdgcn_mfma_f32_16x16x32_bf16(
              af[mt], bfv[nt], acc[mt][nt], 0, 0, 0);
    }
  }

  // epilogue: C/D layout col = lane&15, row = (lane>>4)*4 + reg; bf16 stores
  u16* Pp = P + (size_t)blockIdx.z * (B_SZ * U_SZ);
#pragma unroll
  for (int mt = 0; mt < 4; ++mt)
#pragma unroll
    for (int rr = 0; rr < 4; ++rr) {
      int row = m0 + wr * 64 + mt * 16 + q * 4 + rr;
      size_t rb = (size_t)row * U_SZ + n0 + wn * 64 + m;
#pragma unroll
      for (int nt = 0; nt < 4; ++nt) Pp[rb + nt * 16] = f2bf(acc[mt][nt][rr]);
    }
}

// ---------------------------------------------------------------------------
// out = sum_s bf16(P[s]) + bias, fp32 accumulate. grid 256 x 256; each thread
// one bf16x8 (8 consecutive outputs): 16B load per split, 2 f32x4 stores.
// ---------------------------------------------------------------------------
__global__ void reduce_kernel(const u16* __restrict__ P,
                              const float* __restrict__ bias,
                              float* __restrict__ out) {
  const int idx = blockIdx.x * 256 + threadIdx.x;  // bf16x8 index, 0..65535
  const int col8 = (idx & 63) * 8;                 // 64 groups of 8 per row
  float acc[8];
#pragma unroll
  for (int j = 0; j < 8; ++j) acc[j] = bias[col8 + j];
#pragma unroll
  for (int s = 0; s < SPLITS; ++s) {
    bf16x8 v = ((const bf16x8*)P)[(size_t)s * (B_SZ * U_SZ / 8) + idx];
#pragma unroll
    for (int j = 0; j < 8; ++j) acc[j] += (float)v[j];
  }
  f32x4 o0, o1;
#pragma unroll
  for (int j = 0; j < 4; ++j) { o0[j] = acc[j]; o1[j] = acc[4 + j]; }
  f32x4* o4 = (f32x4*)out;
  o4[idx * 2]     = o0;
  o4[idx * 2 + 1] = o1;
}

extern "C" void kernel_launch(void* const* d_in, const int* in_sizes, int n_in,
                              void* d_out, int out_size, void* d_ws, size_t ws_size,
                              hipStream_t stream) {
  const float* X    = (const float*)d_in[0];  // (1024, 512)
  const float* SK   = (const float*)d_in[1];  // (512, 8, 512)
  const float* SF   = (const float*)d_in[2];  // (512, 512)
  const float* bias = (const float*)d_in[3];  // (512,)

  char* ws = (char*)d_ws;
  u16* WT = (u16*)ws;                       // 512*4608*2  = 4,718,592 B
  u16* A  = (u16*)(ws + 4718592);           // 1024*4608*2 = 9,437,184 B
  u16* P  = (u16*)(ws + 4718592 + 9437184); // 8*1024*512*2 = 8,388,608 B

  hipLaunchKernelGGL(prep_all,      dim3(2560),    dim3(256), 0, stream, SK, SF, X, WT, A);
  hipLaunchKernelGGL(gemm_kan,      dim3(8, 4, 8), dim3(256), 0, stream, A, WT, P);
  hipLaunchKernelGGL(reduce_kernel, dim3(256),     dim3(256), 0, stream, P, bias, (float*)d_out);
}